// Round 10
// baseline (431.213 us; speedup 1.0000x reference)
//
#include <hip/hip_runtime.h>
#include <hip/hip_bf16.h>

// Problem constants
#define B_  4
#define N_  16
#define T_  2048
#define F_  512
#define NC_ 43
constexpr float LN_EPS = 1e-5f;

constexpr int EMB1_N = NC_ * F_;            // 22016 (fp32)
constexpr int WBOX_N = F_ * 4;              // 2048  (fp32)
constexpr int W2BF_N = F_ * F_;             // 262144 (bf16) native [f][c]
constexpr int WMT_N  = F_ * N_ * F_;        // 4194304 (bf16), wmT[f][k], k=n*F+c
constexpr int K_TOT  = N_ * F_;             // 8192
constexpr long long GBUF_N = (long long)B_ * T_ * N_ * F_;   // 67108864 elems

typedef __bf16 bf16x8_t __attribute__((ext_vector_type(8)));
typedef float  f32x4_t  __attribute__((ext_vector_type(4)));

__device__ __forceinline__ void gload16(const void* g, void* l) {
  __builtin_amdgcn_global_load_lds(
      (const __attribute__((address_space(1))) unsigned int*)g,
      (__attribute__((address_space(3))) unsigned int*)l, 16, 0, 0);
}

__device__ __forceinline__ short bf16s(float x) {
  return (short)__bfloat16_as_ushort(__float2bfloat16(x));
}
__device__ __forceinline__ unsigned bf16u(float x) {
  return (unsigned)__bfloat16_as_ushort(__float2bfloat16(x));
}

// ---------------------------------------------------------------------------
// K0a: emb1[k][f] = sum_c emb_table[k][c] * W1[f][c]
//      wbox[f][q] = sum_c W1[f][F+c] * W_lin[c][q]
//      w2bf[f][c] = bf16(W2[f][c])
// ---------------------------------------------------------------------------
__global__ __launch_bounds__(256) void precompute_small(
    const float* __restrict__ emb_table, const float* __restrict__ W1,
    const float* __restrict__ W_lin, const float* __restrict__ W2,
    float* __restrict__ emb1, float* __restrict__ wbox,
    __hip_bfloat16* __restrict__ w2bf)
{
  int idx = blockIdx.x * 256 + threadIdx.x;
  if (idx < EMB1_N) {
    int k = idx >> 9, f = idx & 511;
    const float4* et = (const float4*)&emb_table[k * F_];
    const float4* w1 = (const float4*)&W1[f * (2 * F_)];
    float s = 0.f;
    for (int c4 = 0; c4 < F_ / 4; ++c4) {
      float4 a = et[c4], b = w1[c4];
      s = fmaf(a.x, b.x, s); s = fmaf(a.y, b.y, s);
      s = fmaf(a.z, b.z, s); s = fmaf(a.w, b.w, s);
    }
    emb1[idx] = s;
  } else if (idx < EMB1_N + WBOX_N) {
    int t2 = idx - EMB1_N;
    int f = t2 >> 2, q = t2 & 3;
    const float4* w1 = (const float4*)&W1[f * (2 * F_) + F_];
    float s = 0.f;
    for (int c4 = 0; c4 < F_ / 4; ++c4) {
      float4 a = w1[c4];
      s = fmaf(a.x, W_lin[(c4 * 4 + 0) * 4 + q], s);
      s = fmaf(a.y, W_lin[(c4 * 4 + 1) * 4 + q], s);
      s = fmaf(a.z, W_lin[(c4 * 4 + 2) * 4 + q], s);
      s = fmaf(a.w, W_lin[(c4 * 4 + 3) * 4 + q], s);
    }
    wbox[t2] = s;
  } else if (idx < EMB1_N + WBOX_N + W2BF_N) {
    int t3 = idx - (EMB1_N + WBOX_N);
    w2bf[t3] = __float2bfloat16(W2[t3]);
  }
}

// ---------------------------------------------------------------------------
// K0b: wmT[f][k], k=n*F+c  <-  Wm[f][c][n].  (r5, proven)
// ---------------------------------------------------------------------------
__global__ __launch_bounds__(256) void precompute_wmT(
    const float* __restrict__ Wm, __hip_bfloat16* __restrict__ wmT)
{
  __shared__ float tile[16 * 517];  // [n][c], 33 KB
  const int f = blockIdx.x;
  const float* src = Wm + (long long)f * 8192;   // [c][n]: idx = c*16+n
  for (int i = threadIdx.x; i < 8192; i += 256) {
    int c = i >> 4, n = i & 15;
    tile[n * 517 + c] = src[i];
  }
  __syncthreads();
  short* dst = (short*)wmT + (long long)f * 8192;  // [n][c]: o = n*512+c
  for (int i = threadIdx.x; i < 4096; i += 256) {
    int o = i << 1;
    int n = o >> 9, c = o & 511;
    short2 sv;
    sv.x = bf16s(tile[n * 517 + c]);
    sv.y = bf16s(tile[n * 517 + c + 1]);
    *(short2*)&dst[o] = sv;
  }
}

// ---------------------------------------------------------------------------
// k_h1g v3 (r3-proven) + pbase chunk offset: BLOCK PER PIXEL.
// pbase: global pixel index of this chunk's first pixel; inputs are read at
// pixel (blockIdx.x + pbase), output g is written at LOCAL pixel blockIdx.x.
// (v4 n1T restructure blacklisted, r4/r5.)
// ---------------------------------------------------------------------------
#define N1ST 20
__global__ __launch_bounds__(256) void k_h1g(
    const float* __restrict__ bbox, const int* __restrict__ cls,
    const float* __restrict__ edge, const float* __restrict__ emb1,
    const float* __restrict__ wbox, __hip_bfloat16* __restrict__ g,
    int pbase)
{
  __shared__ __align__(16) short em_bf[256];            // em[i][j] bf16
  __shared__ __align__(16) short n1T[F_ * N1ST + 32];   // node1T [f][j]
  __shared__ int   cls_s[N_];
  __shared__ float bb_s[N_ * 4];

  const int p = blockIdx.x;          // local pixel (g index)
  const int pg = p + pbase;          // global pixel (input index)
  const int b = pg >> 11;
  const int t = pg & 2047;
  const int tid = threadIdx.x;

  {
    int i = tid >> 4, j = tid & 15;
    em_bf[tid] = bf16s(edge[(((b * N_ + i) * N_ + j) * T_) + t]);
  }
  if (tid < N_) cls_s[tid] = cls[(b * N_ + tid) * T_ + t];
  if (tid < N_ * 4) {
    int j = tid >> 2, qq = tid & 3;
    bb_s[tid] = bbox[(((b * N_ + j) * 4 + qq) * T_) + t];
  }
  __syncthreads();

  // n1T[f][j] = emb1[cls[j]][f] + bb[j][:] . wbox[f][:]   (float4 over f)
  const float4* wb4 = (const float4*)wbox;
  for (int idx = tid; idx < N_ * F_ / 4; idx += 256) {
    int j = idx >> 7, f4 = idx & 127;
    float4 e = *(const float4*)&emb1[cls_s[j] * F_ + f4 * 4];
    float b0 = bb_s[j * 4 + 0], b1 = bb_s[j * 4 + 1];
    float b2 = bb_s[j * 4 + 2], b3 = bb_s[j * 4 + 3];
    float4 w0 = wb4[f4 * 4 + 0], w1 = wb4[f4 * 4 + 1];
    float4 w2 = wb4[f4 * 4 + 2], w3 = wb4[f4 * 4 + 3];
    int f = f4 * 4;
    float v0 = e.x; v0 = fmaf(b0, w0.x, v0); v0 = fmaf(b1, w0.y, v0);
    v0 = fmaf(b2, w0.z, v0); v0 = fmaf(b3, w0.w, v0);
    float v1 = e.y; v1 = fmaf(b0, w1.x, v1); v1 = fmaf(b1, w1.y, v1);
    v1 = fmaf(b2, w1.z, v1); v1 = fmaf(b3, w1.w, v1);
    float v2 = e.z; v2 = fmaf(b0, w2.x, v2); v2 = fmaf(b1, w2.y, v2);
    v2 = fmaf(b2, w2.z, v2); v2 = fmaf(b3, w2.w, v2);
    float v3 = e.w; v3 = fmaf(b0, w3.x, v3); v3 = fmaf(b1, w3.y, v3);
    v3 = fmaf(b2, w3.z, v3); v3 = fmaf(b3, w3.w, v3);
    n1T[(f + 0) * N1ST + j] = bf16s(v0);
    n1T[(f + 1) * N1ST + j] = bf16s(v1);
    n1T[(f + 2) * N1ST + j] = bf16s(v2);
    n1T[(f + 3) * N1ST + j] = bf16s(v3);
  }
  __syncthreads();

  const int lane = tid & 63, wv = tid >> 6;
  const int c = lane & 15;
  const int q = lane >> 4;

  union { bf16x8_t v; short4 s[2]; } ef;
  ef.s[0] = (short4){0, 0, 0, 0};
  ef.s[1] = (short4){0, 0, 0, 0};
  if (q < 2) {
    ef.s[0] = *(const short4*)&em_bf[c * 16 + 8 * q];
    ef.s[1] = *(const short4*)&em_bf[c * 16 + 8 * q + 4];
  }
  const int ko = (q < 2) ? 8 * q : 0;
  // bpermute source byte-addresses for the d1->d2 lane exchange
  const int a0 = ((32 * q + c) & 63) * 4;
  const int a1 = ((32 * q + 16 + c) & 63) * 4;

  short* gs = (short*)g;
  const long long gbase = (long long)p * (N_ * F_);

#pragma unroll
  for (int tl = 0; tl < 8; ++tl) {
    const int ft = wv * 8 + tl;
    const int row = (ft * 16 + c) * N1ST;

    union { bf16x8_t v; short4 s[2]; } bf_;
    bf_.s[0] = *(const short4*)&n1T[row + ko];
    bf_.s[1] = *(const short4*)&n1T[row + ko + 4];
    f32x4_t d1 = __builtin_amdgcn_mfma_f32_16x16x32_bf16(
        ef.v, bf_.v, (f32x4_t){0.f, 0.f, 0.f, 0.f}, 0, 0, 0);

    // lane (c,q) holds h1[i=4q+r][f=ft*16+c]; pack relu'd bf16 pairs
    int pk0 = (int)((bf16u(fmaxf(d1[1], 0.f)) << 16) | bf16u(fmaxf(d1[0], 0.f)));
    int pk1 = (int)((bf16u(fmaxf(d1[3], 0.f)) << 16) | bf16u(fmaxf(d1[2], 0.f)));

    union { bf16x8_t v; int u[4]; } af_;
    af_.u[0] = __builtin_amdgcn_ds_bpermute(a0, pk0);
    af_.u[1] = __builtin_amdgcn_ds_bpermute(a0, pk1);
    af_.u[2] = __builtin_amdgcn_ds_bpermute(a1, pk0);
    af_.u[3] = __builtin_amdgcn_ds_bpermute(a1, pk1);

    f32x4_t d2 = __builtin_amdgcn_mfma_f32_16x16x32_bf16(
        af_.v, ef.v, (f32x4_t){0.f, 0.f, 0.f, 0.f}, 0, 0, 0);
    short4 gv;
    gv.x = bf16s(d2[0]);
    gv.y = bf16s(d2[1]);
    gv.z = bf16s(d2[2]);
    gv.w = bf16s(d2[3]);
    *(short4*)&gs[gbase + c * F_ + ft * 16 + 4 * q] = gv;
  }
}

// ---------------------------------------------------------------------------
// gemm_h2_d3 (r9, HW-validated): h2out = relu(gIn @ w2bf^T), SEPARATE OUT.
// DEPTH-3 counted-vmcnt pipeline, BM=128, BN=256, BK=32, 512 threads.
// ---------------------------------------------------------------------------
__device__ __forceinline__ void stage_d3(const short* gs, const short* ws,
                                         long long m0, int n0, int kc,
                                         short* As, short* Bs,
                                         int rowU, int chkU) {
  gload16(gs + (m0 + rowU) * F_ + kc + chkU, As + rowU * 32 + chkU);
#pragma unroll
  for (int it = 0; it < 2; ++it)
    gload16(ws + (n0 + it * 128 + rowU) * F_ + kc + chkU,
            Bs + (it * 128 + rowU) * 32 + chkU);
}

__global__ __launch_bounds__(512, 2) void gemm_h2_d3(
    const __hip_bfloat16* __restrict__ gIn,
    const __hip_bfloat16* __restrict__ w2bf,
    __hip_bfloat16* __restrict__ h2out)
{
  __shared__ __align__(16) short As[3][128 * 32];  // 3 x 8 KB
  __shared__ __align__(16) short Bs[3][256 * 32];  // 3 x 16 KB

  const short* gs = (const short*)gIn;
  const short* ws = (const short*)w2bf;
  short* hs = (short*)h2out;

  const int tid = threadIdx.x;
  const int bx = blockIdx.x;
  const int mt = (bx & 7) | ((bx >> 4) << 3);   // pairs nt on same XCD
  const int nt = (bx >> 3) & 1;
  const long long m0 = (long long)mt * 128;
  const int n0 = nt * 256;

  const int wave8 = tid >> 6, lane = tid & 63;
  const int wr = wave8 >> 2, wcol = wave8 & 3;   // 2 x 4 waves, tile 64x64
  const int rowU = tid >> 2, chkU = (tid & 3) * 8;
  const int mrow = lane & 15, kq = (lane >> 4) * 8;

  f32x4_t acc[4][4];
#pragma unroll
  for (int i = 0; i < 4; ++i)
#pragma unroll
    for (int j = 0; j < 4; ++j) acc[i][j] = (f32x4_t){0.f, 0.f, 0.f, 0.f};

  auto compute = [&](const short* Ap, const short* Bp) {
    bf16x8_t af[4], bfr[4];
#pragma unroll
    for (int i = 0; i < 4; ++i)
      af[i] = *(const bf16x8_t*)&Ap[((wr << 6) + i * 16 + mrow) * 32 + kq];
#pragma unroll
    for (int j = 0; j < 4; ++j)
      bfr[j] = *(const bf16x8_t*)&Bp[((wcol << 6) + j * 16 + mrow) * 32 + kq];
    __builtin_amdgcn_s_setprio(1);
#pragma unroll
    for (int i = 0; i < 4; ++i)
#pragma unroll
      for (int j = 0; j < 4; ++j)
        acc[i][j] = __builtin_amdgcn_mfma_f32_16x16x32_bf16(af[i], bfr[j], acc[i][j], 0, 0, 0);
    __builtin_amdgcn_s_setprio(0);
  };

  // prologue: three stages in flight (3 loads each = 9 outstanding)
  stage_d3(gs, ws, m0, n0, 0,  As[0], Bs[0], rowU, chkU);
  stage_d3(gs, ws, m0, n0, 32, As[1], Bs[1], rowU, chkU);
  stage_d3(gs, ws, m0, n0, 64, As[2], Bs[2], rowU, chkU);

  for (int t = 0; t < 13; ++t) {
    asm volatile("s_waitcnt vmcnt(6)" ::: "memory");   // stage t landed (own)
    __builtin_amdgcn_sched_barrier(0);
    __builtin_amdgcn_s_barrier();                       // everyone's landed
    __builtin_amdgcn_sched_barrier(0);

    const int s = t % 3;
    compute(As[s], Bs[s]);

    __builtin_amdgcn_sched_barrier(0);
    __builtin_amdgcn_s_barrier();                       // all reads of buf done
    __builtin_amdgcn_sched_barrier(0);
    stage_d3(gs, ws, m0, n0, (t + 3) * 32, As[s], Bs[s], rowU, chkU);
  }
  // t = 13 (stages 13,14,15 outstanding = 9 loads)
  asm volatile("s_waitcnt vmcnt(6)" ::: "memory");
  __builtin_amdgcn_sched_barrier(0);
  __builtin_amdgcn_s_barrier();
  __builtin_amdgcn_sched_barrier(0);
  compute(As[1], Bs[1]);
  // t = 14
  asm volatile("s_waitcnt vmcnt(3)" ::: "memory");
  __builtin_amdgcn_sched_barrier(0);
  __builtin_amdgcn_s_barrier();
  __builtin_amdgcn_sched_barrier(0);
  compute(As[2], Bs[2]);
  // t = 15
  asm volatile("s_waitcnt vmcnt(0)" ::: "memory");
  __builtin_amdgcn_sched_barrier(0);
  __builtin_amdgcn_s_barrier();
  __builtin_amdgcn_sched_barrier(0);
  compute(As[0], Bs[0]);

  const int rbase = (lane >> 4) << 2;
#pragma unroll
  for (int i = 0; i < 4; ++i)
#pragma unroll
    for (int j = 0; j < 4; ++j)
#pragma unroll
      for (int r = 0; r < 4; ++r) {
        int row = (wr << 6) + i * 16 + rbase + r;
        int col = n0 + (wcol << 6) + j * 16 + mrow;
        float v = fmaxf(acc[i][j][r], 0.f);
        hs[(m0 + row) * F_ + col] = bf16s(v);
      }
}

// ---------------------------------------------------------------------------
// gemm_h2_ip (r6-green FALLBACK, verbatim): in-place depth-2, BN=512.
// ---------------------------------------------------------------------------
__device__ __forceinline__ void stage_ip(const short* gs, const short* ws,
                                         long long m0, int kc,
                                         short* As, short* Bs,
                                         int rowU, int chkU) {
  gload16(gs + (m0 + rowU) * F_ + kc + chkU, As + rowU * 32 + chkU);
#pragma unroll
  for (int it = 0; it < 4; ++it)
    gload16(ws + (it * 128 + rowU) * F_ + kc + chkU,
            Bs + (it * 128 + rowU) * 32 + chkU);
}

__global__ __launch_bounds__(512, 2) void gemm_h2_ip(
    __hip_bfloat16* __restrict__ gbuf, const __hip_bfloat16* __restrict__ w2bf)
{
  __shared__ __align__(16) short As[2][128 * 32];  // 16 KB
  __shared__ __align__(16) short Bs[2][512 * 32];  // 64 KB

  short* gs = (short*)gbuf;
  const short* ws = (const short*)w2bf;

  const int tid = threadIdx.x;
  const long long m0 = (long long)blockIdx.x * 128;
  const int wave8 = tid >> 6, lane = tid & 63;
  const int wr = wave8 >> 2, wcol = wave8 & 3;
  const int rowU = tid >> 2, chkU = (tid & 3) * 8;
  const int mrow = lane & 15, kq = (lane >> 4) * 8;

  f32x4_t acc[4][8];
#pragma unroll
  for (int i = 0; i < 4; ++i)
#pragma unroll
    for (int j = 0; j < 8; ++j) acc[i][j] = (f32x4_t){0.f, 0.f, 0.f, 0.f};

  auto compute = [&](const short* Ap, const short* Bp) {
    bf16x8_t af[4], bfr[8];
#pragma unroll
    for (int i = 0; i < 4; ++i)
      af[i] = *(const bf16x8_t*)&Ap[((wr << 6) + i * 16 + mrow) * 32 + kq];
#pragma unroll
    for (int j = 0; j < 8; ++j)
      bfr[j] = *(const bf16x8_t*)&Bp[((wcol << 7) + j * 16 + mrow) * 32 + kq];
    __builtin_amdgcn_s_setprio(1);
#pragma unroll
    for (int i = 0; i < 4; ++i)
#pragma unroll
      for (int j = 0; j < 8; ++j)
        acc[i][j] = __builtin_amdgcn_mfma_f32_16x16x32_bf16(af[i], bfr[j], acc[i][j], 0, 0, 0);
    __builtin_amdgcn_s_setprio(0);
  };

  stage_ip(gs, ws, m0, 0,  As[0], Bs[0], rowU, chkU);
  stage_ip(gs, ws, m0, 32, As[1], Bs[1], rowU, chkU);

  for (int t = 0; t < 14; ++t) {
    asm volatile("s_waitcnt vmcnt(5)" ::: "memory");
    __builtin_amdgcn_sched_barrier(0);
    __builtin_amdgcn_s_barrier();
    __builtin_amdgcn_sched_barrier(0);

    compute(As[t & 1], Bs[t & 1]);

    __builtin_amdgcn_sched_barrier(0);
    __builtin_amdgcn_s_barrier();
    __builtin_amdgcn_sched_barrier(0);
    stage_ip(gs, ws, m0, (t + 2) * 32, As[t & 1], Bs[t & 1], rowU, chkU);
  }
  asm volatile("s_waitcnt vmcnt(5)" ::: "memory");
  __builtin_amdgcn_sched_barrier(0);
  __builtin_amdgcn_s_barrier();
  __builtin_amdgcn_sched_barrier(0);
  compute(As[0], Bs[0]);
  asm volatile("s_waitcnt vmcnt(0)" ::: "memory");
  __builtin_amdgcn_sched_barrier(0);
  __builtin_amdgcn_s_barrier();
  __builtin_amdgcn_sched_barrier(0);
  compute(As[1], Bs[1]);

  const int rbase = (lane >> 4) << 2;
#pragma unroll
  for (int i = 0; i < 4; ++i)
#pragma unroll
    for (int j = 0; j < 8; ++j)
#pragma unroll
      for (int r = 0; r < 4; ++r) {
        int row = (wr << 6) + i * 16 + rbase + r;
        int col = (wcol << 7) + j * 16 + mrow;
        float v = fmaxf(acc[i][j][r], 0.f);
        gs[(m0 + row) * F_ + col] = bf16s(v);
      }
}

// ---------------------------------------------------------------------------
// gemm_feat v2 (this round): DEPTH-3 counted-vmcnt pipeline at BK=32
// substage granularity.  feat = h2 @ wmT^T -> unnormalized out[b][f][t].
// BM=64, BN=128, in-block split-K2, 512 threads, wave tile 32x64.
// 128 substages (u: abs k = half*4096 + u*32); 3 loads/thread/substage;
// 3 buffers x 24 KB = 72 KB (2 blocks/CU = the grid limit, no occ loss).
// Schedule shape identical to HW-validated gemm_h2_d3: vmcnt(6) steady,
// tail 6->3->0.  h2 read-only, out disjoint -> no in-place hazard.
// ---------------------------------------------------------------------------
__device__ __forceinline__ void stage_feat(const short* aBase, const short* bBase,
                                           char* bufBase, int u,
                                           int hA, int rA, int kA,
                                           int rowB, int chkB) {
  // A: this thread stages its K-half only (256 threads per half)
  gload16(aBase + (long long)rA * K_TOT + hA * 4096 + u * 32 + kA,
          (short*)(bufBase + hA * 4096) + rA * 32 + kA);
  // B: both K-halves
#pragma unroll
  for (int h = 0; h < 2; ++h)
    gload16(bBase + (long long)rowB * K_TOT + h * 4096 + u * 32 + chkB,
            (short*)(bufBase + 8192 + h * 8192) + rowB * 32 + chkB);
}

__global__ __launch_bounds__(512, 2) void gemm_feat(
    const __hip_bfloat16* __restrict__ h2g, const __hip_bfloat16* __restrict__ wmTg,
    float* __restrict__ out)
{
  __shared__ __align__(16) char smem[73728];   // 3 x 24 KB pipeline buffers
  float* sM = (float*)smem;                  // merge [32][132]  (16.9 KB)
  float* sT = (float*)smem;                  // transpose [64][65] (16.6 KB)

  const short* h2s  = (const short*)h2g;
  const short* wmTs = (const short*)wmTg;

  const int tid = threadIdx.x;
  const int bx = blockIdx.x;
  const int mt = bx & 127, nt = bx >> 7;     // XCD-aware: same mt -> same bx%8
  const long long m0 = (long long)mt * 64;
  const int n0 = nt * 128;

  const int wave8 = tid >> 6;
  const int half = wave8 >> 2;      // K-half of this wave
  const int wave = wave8 & 3;
  const int lane = tid & 63;
  const int wr = wave >> 1, wc = wave & 1;   // rows wr*32, cols wc*64
  const int mrow = lane & 15;
  const int kq = (lane >> 4) * 8;

  const short* aBase = h2s + m0 * K_TOT;
  const short* bBase = wmTs + (long long)n0 * K_TOT;

  const int rowB = tid >> 2, chkB = (tid & 3) * 8;       // B: 128 rows
  const int hA = tid >> 8;                               // A: half this thread stages
  const int rA = (tid & 255) >> 2;
  const int kA = (tid & 3) * 8;

  f32x4_t acc[2][4];
#pragma unroll
  for (int i = 0; i < 2; ++i)
#pragma unroll
    for (int j = 0; j < 4; ++j) acc[i][j] = (f32x4_t){0.f, 0.f, 0.f, 0.f};

  auto computeU = [&](char* bufBase) {
    const short* AsH = (const short*)(bufBase + half * 4096);
    const short* BsH = (const short*)(bufBase + 8192 + half * 8192);
    bf16x8_t af[2], bfr[4];
#pragma unroll
    for (int i = 0; i < 2; ++i)
      af[i] = *(const bf16x8_t*)&AsH[((wr << 5) + i * 16 + mrow) * 32 + kq];
#pragma unroll
    for (int j = 0; j < 4; ++j)
      bfr[j] = *(const bf16x8_t*)&BsH[((wc << 6) + j * 16 + mrow) * 32 + kq];
    __builtin_amdgcn_s_setprio(1);
#pragma unroll
    for (int i = 0; i < 2; ++i)
#pragma unroll
      for (int j = 0; j < 4; ++j)
        acc[i][j] = __builtin_amdgcn_mfma_f32_16x16x32_bf16(af[i], bfr[j], acc[i][j], 0, 0, 0);
    __builtin_amdgcn_s_setprio(0);
  };

  // prologue: 3 substages in flight (3 loads each = 9 outstanding)
  stage_feat(aBase, bBase, smem + 0 * 24576, 0, hA, rA, kA, rowB, chkB);
  stage_feat(aBase, bBase, smem + 1 * 24576, 1, hA, rA, kA, rowB, chkB);
  stage_feat(aBase, bBase, smem + 2 * 24576, 2, hA, rA, kA, rowB, chkB);

  for (int u = 0; u < 125; ++u) {
    asm volatile("s_waitcnt vmcnt(6)" ::: "memory");   // substage u landed (own)
    __builtin_amdgcn_sched_barrier(0);
    __builtin_amdgcn_s_barrier();                       // everyone's landed
    __builtin_amdgcn_sched_barrier(0);

    char* buf = smem + (u % 3) * 24576;
    computeU(buf);

    __builtin_amdgcn_sched_barrier(0);
    __builtin_amdgcn_s_barrier();                       // all reads of buf done
    __builtin_amdgcn_sched_barrier(0);
    stage_feat(aBase, bBase, buf, u + 3, hA, rA, kA, rowB, chkB);
  }
  // u = 125 (substages 125,126,127 outstanding = 9 loads)
  asm volatile("s_waitcnt vmcnt(6)" ::: "memory");
  __builtin_amdgcn_sched_barrier(0);
  __builtin_amdgcn_s_barrier();
  __builtin_amdgcn_sched_barrier(0);
  computeU(smem + (125 % 3) * 24576);
  // u = 126
  asm volatile("s_waitcnt vmcnt(3)" ::: "memory");
  __builtin_amdgcn_sched_barrier(0);
  __builtin_amdgcn_s_barrier();
  __builtin_amdgcn_sched_barrier(0);
  computeU(smem + (126 % 3) * 24576);
  // u = 127
  asm volatile("s_waitcnt vmcnt(0)" ::: "memory");
  __builtin_amdgcn_sched_barrier(0);
  __builtin_amdgcn_s_barrier();
  __builtin_amdgcn_sched_barrier(0);
  computeU(smem + (127 % 3) * 24576);

  // all loads landed (vmcnt 0) and all waves past final compute:
  __builtin_amdgcn_sched_barrier(0);
  __builtin_amdgcn_s_barrier();
  __builtin_amdgcn_sched_barrier(0);

  // merge: half-1 accs into half-0 waves, 2 row-rounds (32 rows each) via sM
  const int rq = (lane >> 4) << 2;
#pragma unroll
  for (int r = 0; r < 2; ++r) {
    if (half == 1 && wr == r) {
#pragma unroll
      for (int i = 0; i < 2; ++i)
#pragma unroll
        for (int j = 0; j < 4; ++j)
#pragma unroll
          for (int rr = 0; rr < 4; ++rr)
            sM[(i * 16 + rq + rr) * 132 + (wc << 6) + j * 16 + mrow] = acc[i][j][rr];
    }
    __syncthreads();
    if (half == 0 && wr == r) {
#pragma unroll
      for (int i = 0; i < 2; ++i)
#pragma unroll
        for (int j = 0; j < 4; ++j)
#pragma unroll
          for (int rr = 0; rr < 4; ++rr)
            acc[i][j][rr] += sM[(i * 16 + rq + rr) * 132 + (wc << 6) + j * 16 + mrow];
    }
    __syncthreads();
  }

  // epilogue: transpose col-chunks of 64 via sT, store unnormalized out[b][f][t]
  const int b = (int)(m0 >> 11);
  const int t0 = (int)(m0 & 2047);
#pragma unroll
  for (int cch = 0; cch < 2; ++cch) {
    if (half == 0 && wc == cch) {
#pragma unroll
      for (int i = 0; i < 2; ++i)
#pragma unroll
        for (int j = 0; j < 4; ++j)
#pragma unroll
          for (int rr = 0; rr < 4; ++rr)
            sT[((wr << 5) + i * 16 + rq + rr) * 65 + j * 16 + mrow] = acc[i][j][rr];
    }
    __syncthreads();
    long long ob = (long long)b * (F_ * T_) + (long long)(n0 + cch * 64) * T_ + t0;
    for (int idx = tid; idx < 64 * 64; idx += 512) {
      int f = idx >> 6, m = idx & 63;
      out[ob + (long long)f * T_ + m] = sT[m * 65 + f];
    }
    __syncthreads();
  }
}

// ---------------------------------------------------------------------------
// LN in-place on out[b][f][t]: per (b,t) normalize over f
// ---------------------------------------------------------------------------
__global__ __launch_bounds__(256) void ln_inplace(
    float* __restrict__ out, const float* __restrict__ lnw, const float* __restrict__ lnb)
{
  __shared__ float sF[F_ * 17];
  __shared__ float red[512];
  __shared__ float smu[16], srstd[16];

  const int tid = threadIdx.x;
  const int p0 = blockIdx.x << 4;
  const int b = p0 >> 11, t0 = p0 & 2047;
  long long ob = (long long)b * (F_ * T_) + t0;

  for (int idx = tid; idx < F_ * 16; idx += 256) {
    int f = idx >> 4, m = idx & 15;
    sF[f * 17 + m] = out[ob + (long long)f * T_ + m];
  }
  __syncthreads();

  {
    int m = tid & 15, s = tid >> 4;
    float sum = 0.f, sq = 0.f;
    for (int f = s; f < F_; f += 16) {
      float v = sF[f * 17 + m];
      sum += v; sq += v * v;
    }
    red[tid] = sum;
    red[256 + tid] = sq;
  }
  __syncthreads();
  if (tid < 16) {
    float sum = 0.f, sq = 0.f;
#pragma unroll
    for (int s = 0; s < 16; ++s) { sum += red[s * 16 + tid]; sq += red[256 + s * 16 + tid]; }
    float mu = sum * (1.f / F_);
    float var = sq * (1.f / F_) - mu * mu;
    smu[tid] = mu;
    srstd[tid] = rsqrtf(var + LN_EPS);
  }
  __syncthreads();

  for (int idx = tid; idx < F_ * 16; idx += 256) {
    int f = idx >> 4, m = idx & 15;
    float v = (sF[f * 17 + m] - smu[m]) * srstd[m] * lnw[f] + lnb[f];
    out[ob + (long long)f * T_ + m] = v;
  }
}

// ---------------------------------------------------------------------------
extern "C" void kernel_launch(void* const* d_in, const int* in_sizes, int n_in,
                              void* d_out, int out_size, void* d_ws, size_t ws_size,
                              hipStream_t stream)
{
  const float* bbox      = (const float*)d_in[0];
  const int*   cls       = (const int*)d_in[1];
  const float* edge      = (const float*)d_in[2];
  const float* W_lin     = (const float*)d_in[3];
  const float* emb_table = (const float*)d_in[4];
  const float* W1        = (const float*)d_in[5];
  const float* W2        = (const float*)d_in[6];
  const float* Wm        = (const float*)d_in[7];
  const float* lnw       = (const float*)d_in[8];
  const float* lnb       = (const float*)d_in[9];
  float* out = (float*)d_out;

  float* emb1 = (float*)d_ws;
  float* wbox = emb1 + EMB1_N;
  __hip_bfloat16* w2bf = (__hip_bfloat16*)(wbox + WBOX_N);
  __hip_bfloat16* wmT  = w2bf + W2BF_N;
  __hip_bfloat16* wsBase = wmT + WMT_N;   // scratch region start

  const size_t base_bytes =
      (size_t)(EMB1_N + WBOX_N) * 4 + (size_t)(W2BF_N + WMT_N) * 2;
  const size_t tier1 = base_bytes + 2ULL * (size_t)GBUF_N * 2;          // g + h2
  const size_t tier2 = base_bytes + (size_t)GBUF_N + (size_t)GBUF_N * 2; // g/2 + h2

  precompute_small<<<(EMB1_N + WBOX_N + W2BF_N) / 256, 256, 0, stream>>>(
      emb_table, W1, W_lin, W2, emb1, wbox, w2bf);
  precompute_wmT<<<F_, 256, 0, stream>>>(Wm, wmT);

  if (ws_size >= tier1) {
    // full g + full h2, single pass
    __hip_bfloat16* gbuf  = wsBase;
    __hip_bfloat16* h2buf = gbuf + GBUF_N;
    k_h1g<<<B_ * T_, 256, 0, stream>>>(bbox, cls, edge, emb1, wbox, gbuf, 0);
    gemm_h2_d3<<<2048, 512, 0, stream>>>(gbuf, w2bf, h2buf);
    gemm_feat<<<512, 512, 0, stream>>>(h2buf, wmT, out);
  } else if (ws_size >= tier2) {
    // half-g scratch (reused), full h2; gemm_feat keeps full grid
    __hip_bfloat16* gHalf = wsBase;                       // GBUF_N/2 elems
    __hip_bfloat16* h2buf = gHalf + GBUF_N / 2;           // GBUF_N elems
    for (int c = 0; c < 2; ++c) {
      k_h1g<<<B_ * T_ / 2, 256, 0, stream>>>(
          bbox, cls, edge, emb1, wbox, gHalf, c * (B_ * T_ / 2));
      gemm_h2_d3<<<1024, 512, 0, stream>>>(
          gHalf, w2bf, h2buf + (long long)c * (GBUF_N / 2));
    }
    gemm_feat<<<512, 512, 0, stream>>>(h2buf, wmT, out);
  } else {
    // r8-green fallback: in-place depth-2
    __hip_bfloat16* gbuf = wsBase;
    k_h1g<<<B_ * T_, 256, 0, stream>>>(bbox, cls, edge, emb1, wbox, gbuf, 0);
    gemm_h2_ip<<<1024, 512, 0, stream>>>(gbuf, w2bf);
    gemm_feat<<<512, 512, 0, stream>>>(gbuf, wmT, out);
  }
  ln_inplace<<<B_ * T_ / 16, 256, 0, stream>>>(out, lnw, lnb);
}

// Round 11
// 401.089 us; speedup vs baseline: 1.0751x; 1.0751x over previous
//
#include <hip/hip_runtime.h>
#include <hip/hip_bf16.h>

// Problem constants
#define B_  4
#define N_  16
#define T_  2048
#define F_  512
#define NC_ 43
constexpr float LN_EPS = 1e-5f;

constexpr int EMB1_N = NC_ * F_;            // 22016 (fp32)
constexpr int WBOX_N = F_ * 4;              // 2048  (fp32)
constexpr int W2BF_N = F_ * F_;             // 262144 (bf16) native [f][c]
constexpr int WMT_N  = F_ * N_ * F_;        // 4194304 (bf16), wmT[f][k], k=n*F+c
constexpr int K_TOT  = N_ * F_;             // 8192
constexpr long long GBUF_N = (long long)B_ * T_ * N_ * F_;   // 67108864 elems

typedef __bf16 bf16x8_t __attribute__((ext_vector_type(8)));
typedef float  f32x4_t  __attribute__((ext_vector_type(4)));

__device__ __forceinline__ void gload16(const void* g, void* l) {
  __builtin_amdgcn_global_load_lds(
      (const __attribute__((address_space(1))) unsigned int*)g,
      (__attribute__((address_space(3))) unsigned int*)l, 16, 0, 0);
}

__device__ __forceinline__ short bf16s(float x) {
  return (short)__bfloat16_as_ushort(__float2bfloat16(x));
}
__device__ __forceinline__ unsigned bf16u(float x) {
  return (unsigned)__bfloat16_as_ushort(__float2bfloat16(x));
}

// ---------------------------------------------------------------------------
// K0a: emb1[k][f] = sum_c emb_table[k][c] * W1[f][c]
//      wbox[f][q] = sum_c W1[f][F+c] * W_lin[c][q]
//      w2bf[f][c] = bf16(W2[f][c])
// ---------------------------------------------------------------------------
__global__ __launch_bounds__(256) void precompute_small(
    const float* __restrict__ emb_table, const float* __restrict__ W1,
    const float* __restrict__ W_lin, const float* __restrict__ W2,
    float* __restrict__ emb1, float* __restrict__ wbox,
    __hip_bfloat16* __restrict__ w2bf)
{
  int idx = blockIdx.x * 256 + threadIdx.x;
  if (idx < EMB1_N) {
    int k = idx >> 9, f = idx & 511;
    const float4* et = (const float4*)&emb_table[k * F_];
    const float4* w1 = (const float4*)&W1[f * (2 * F_)];
    float s = 0.f;
    for (int c4 = 0; c4 < F_ / 4; ++c4) {
      float4 a = et[c4], b = w1[c4];
      s = fmaf(a.x, b.x, s); s = fmaf(a.y, b.y, s);
      s = fmaf(a.z, b.z, s); s = fmaf(a.w, b.w, s);
    }
    emb1[idx] = s;
  } else if (idx < EMB1_N + WBOX_N) {
    int t2 = idx - EMB1_N;
    int f = t2 >> 2, q = t2 & 3;
    const float4* w1 = (const float4*)&W1[f * (2 * F_) + F_];
    float s = 0.f;
    for (int c4 = 0; c4 < F_ / 4; ++c4) {
      float4 a = w1[c4];
      s = fmaf(a.x, W_lin[(c4 * 4 + 0) * 4 + q], s);
      s = fmaf(a.y, W_lin[(c4 * 4 + 1) * 4 + q], s);
      s = fmaf(a.z, W_lin[(c4 * 4 + 2) * 4 + q], s);
      s = fmaf(a.w, W_lin[(c4 * 4 + 3) * 4 + q], s);
    }
    wbox[t2] = s;
  } else if (idx < EMB1_N + WBOX_N + W2BF_N) {
    int t3 = idx - (EMB1_N + WBOX_N);
    w2bf[t3] = __float2bfloat16(W2[t3]);
  }
}

// ---------------------------------------------------------------------------
// K0b: wmT[f][k], k=n*F+c  <-  Wm[f][c][n].  (r5, proven)
// ---------------------------------------------------------------------------
__global__ __launch_bounds__(256) void precompute_wmT(
    const float* __restrict__ Wm, __hip_bfloat16* __restrict__ wmT)
{
  __shared__ float tile[16 * 517];  // [n][c], 33 KB
  const int f = blockIdx.x;
  const float* src = Wm + (long long)f * 8192;   // [c][n]: idx = c*16+n
  for (int i = threadIdx.x; i < 8192; i += 256) {
    int c = i >> 4, n = i & 15;
    tile[n * 517 + c] = src[i];
  }
  __syncthreads();
  short* dst = (short*)wmT + (long long)f * 8192;  // [n][c]: o = n*512+c
  for (int i = threadIdx.x; i < 4096; i += 256) {
    int o = i << 1;
    int n = o >> 9, c = o & 511;
    short2 sv;
    sv.x = bf16s(tile[n * 517 + c]);
    sv.y = bf16s(tile[n * 517 + c + 1]);
    *(short2*)&dst[o] = sv;
  }
}

// ---------------------------------------------------------------------------
// k_h1g v3 (r3-proven) + pbase chunk offset: BLOCK PER PIXEL.
// (v4 n1T restructure blacklisted, r4/r5.)
// ---------------------------------------------------------------------------
#define N1ST 20
__global__ __launch_bounds__(256) void k_h1g(
    const float* __restrict__ bbox, const int* __restrict__ cls,
    const float* __restrict__ edge, const float* __restrict__ emb1,
    const float* __restrict__ wbox, __hip_bfloat16* __restrict__ g,
    int pbase)
{
  __shared__ __align__(16) short em_bf[256];            // em[i][j] bf16
  __shared__ __align__(16) short n1T[F_ * N1ST + 32];   // node1T [f][j]
  __shared__ int   cls_s[N_];
  __shared__ float bb_s[N_ * 4];

  const int p = blockIdx.x;          // local pixel (g index)
  const int pg = p + pbase;          // global pixel (input index)
  const int b = pg >> 11;
  const int t = pg & 2047;
  const int tid = threadIdx.x;

  {
    int i = tid >> 4, j = tid & 15;
    em_bf[tid] = bf16s(edge[(((b * N_ + i) * N_ + j) * T_) + t]);
  }
  if (tid < N_) cls_s[tid] = cls[(b * N_ + tid) * T_ + t];
  if (tid < N_ * 4) {
    int j = tid >> 2, qq = tid & 3;
    bb_s[tid] = bbox[(((b * N_ + j) * 4 + qq) * T_) + t];
  }
  __syncthreads();

  // n1T[f][j] = emb1[cls[j]][f] + bb[j][:] . wbox[f][:]   (float4 over f)
  const float4* wb4 = (const float4*)wbox;
  for (int idx = tid; idx < N_ * F_ / 4; idx += 256) {
    int j = idx >> 7, f4 = idx & 127;
    float4 e = *(const float4*)&emb1[cls_s[j] * F_ + f4 * 4];
    float b0 = bb_s[j * 4 + 0], b1 = bb_s[j * 4 + 1];
    float b2 = bb_s[j * 4 + 2], b3 = bb_s[j * 4 + 3];
    float4 w0 = wb4[f4 * 4 + 0], w1 = wb4[f4 * 4 + 1];
    float4 w2 = wb4[f4 * 4 + 2], w3 = wb4[f4 * 4 + 3];
    int f = f4 * 4;
    float v0 = e.x; v0 = fmaf(b0, w0.x, v0); v0 = fmaf(b1, w0.y, v0);
    v0 = fmaf(b2, w0.z, v0); v0 = fmaf(b3, w0.w, v0);
    float v1 = e.y; v1 = fmaf(b0, w1.x, v1); v1 = fmaf(b1, w1.y, v1);
    v1 = fmaf(b2, w1.z, v1); v1 = fmaf(b3, w1.w, v1);
    float v2 = e.z; v2 = fmaf(b0, w2.x, v2); v2 = fmaf(b1, w2.y, v2);
    v2 = fmaf(b2, w2.z, v2); v2 = fmaf(b3, w2.w, v2);
    float v3 = e.w; v3 = fmaf(b0, w3.x, v3); v3 = fmaf(b1, w3.y, v3);
    v3 = fmaf(b2, w3.z, v3); v3 = fmaf(b3, w3.w, v3);
    n1T[(f + 0) * N1ST + j] = bf16s(v0);
    n1T[(f + 1) * N1ST + j] = bf16s(v1);
    n1T[(f + 2) * N1ST + j] = bf16s(v2);
    n1T[(f + 3) * N1ST + j] = bf16s(v3);
  }
  __syncthreads();

  const int lane = tid & 63, wv = tid >> 6;
  const int c = lane & 15;
  const int q = lane >> 4;

  union { bf16x8_t v; short4 s[2]; } ef;
  ef.s[0] = (short4){0, 0, 0, 0};
  ef.s[1] = (short4){0, 0, 0, 0};
  if (q < 2) {
    ef.s[0] = *(const short4*)&em_bf[c * 16 + 8 * q];
    ef.s[1] = *(const short4*)&em_bf[c * 16 + 8 * q + 4];
  }
  const int ko = (q < 2) ? 8 * q : 0;
  // bpermute source byte-addresses for the d1->d2 lane exchange
  const int a0 = ((32 * q + c) & 63) * 4;
  const int a1 = ((32 * q + 16 + c) & 63) * 4;

  short* gs = (short*)g;
  const long long gbase = (long long)p * (N_ * F_);

#pragma unroll
  for (int tl = 0; tl < 8; ++tl) {
    const int ft = wv * 8 + tl;
    const int row = (ft * 16 + c) * N1ST;

    union { bf16x8_t v; short4 s[2]; } bf_;
    bf_.s[0] = *(const short4*)&n1T[row + ko];
    bf_.s[1] = *(const short4*)&n1T[row + ko + 4];
    f32x4_t d1 = __builtin_amdgcn_mfma_f32_16x16x32_bf16(
        ef.v, bf_.v, (f32x4_t){0.f, 0.f, 0.f, 0.f}, 0, 0, 0);

    // lane (c,q) holds h1[i=4q+r][f=ft*16+c]; pack relu'd bf16 pairs
    int pk0 = (int)((bf16u(fmaxf(d1[1], 0.f)) << 16) | bf16u(fmaxf(d1[0], 0.f)));
    int pk1 = (int)((bf16u(fmaxf(d1[3], 0.f)) << 16) | bf16u(fmaxf(d1[2], 0.f)));

    union { bf16x8_t v; int u[4]; } af_;
    af_.u[0] = __builtin_amdgcn_ds_bpermute(a0, pk0);
    af_.u[1] = __builtin_amdgcn_ds_bpermute(a0, pk1);
    af_.u[2] = __builtin_amdgcn_ds_bpermute(a1, pk0);
    af_.u[3] = __builtin_amdgcn_ds_bpermute(a1, pk1);

    f32x4_t d2 = __builtin_amdgcn_mfma_f32_16x16x32_bf16(
        af_.v, ef.v, (f32x4_t){0.f, 0.f, 0.f, 0.f}, 0, 0, 0);
    short4 gv;
    gv.x = bf16s(d2[0]);
    gv.y = bf16s(d2[1]);
    gv.z = bf16s(d2[2]);
    gv.w = bf16s(d2[3]);
    *(short4*)&gs[gbase + c * F_ + ft * 16 + 4 * q] = gv;
  }
}

// ---------------------------------------------------------------------------
// gemm_h2_d3 (r9, HW-validated): h2out = relu(gIn @ w2bf^T), SEPARATE OUT.
// DEPTH-3 counted-vmcnt pipeline, BM=128, BN=256, BK=32, 512 threads.
// ---------------------------------------------------------------------------
__device__ __forceinline__ void stage_d3(const short* gs, const short* ws,
                                         long long m0, int n0, int kc,
                                         short* As, short* Bs,
                                         int rowU, int chkU) {
  gload16(gs + (m0 + rowU) * F_ + kc + chkU, As + rowU * 32 + chkU);
#pragma unroll
  for (int it = 0; it < 2; ++it)
    gload16(ws + (n0 + it * 128 + rowU) * F_ + kc + chkU,
            Bs + (it * 128 + rowU) * 32 + chkU);
}

__global__ __launch_bounds__(512, 2) void gemm_h2_d3(
    const __hip_bfloat16* __restrict__ gIn,
    const __hip_bfloat16* __restrict__ w2bf,
    __hip_bfloat16* __restrict__ h2out)
{
  __shared__ __align__(16) short As[3][128 * 32];  // 3 x 8 KB
  __shared__ __align__(16) short Bs[3][256 * 32];  // 3 x 16 KB

  const short* gs = (const short*)gIn;
  const short* ws = (const short*)w2bf;
  short* hs = (short*)h2out;

  const int tid = threadIdx.x;
  const int bx = blockIdx.x;
  const int mt = (bx & 7) | ((bx >> 4) << 3);   // pairs nt on same XCD
  const int nt = (bx >> 3) & 1;
  const long long m0 = (long long)mt * 128;
  const int n0 = nt * 256;

  const int wave8 = tid >> 6, lane = tid & 63;
  const int wr = wave8 >> 2, wcol = wave8 & 3;   // 2 x 4 waves, tile 64x64
  const int rowU = tid >> 2, chkU = (tid & 3) * 8;
  const int mrow = lane & 15, kq = (lane >> 4) * 8;

  f32x4_t acc[4][4];
#pragma unroll
  for (int i = 0; i < 4; ++i)
#pragma unroll
    for (int j = 0; j < 4; ++j) acc[i][j] = (f32x4_t){0.f, 0.f, 0.f, 0.f};

  auto compute = [&](const short* Ap, const short* Bp) {
    bf16x8_t af[4], bfr[4];
#pragma unroll
    for (int i = 0; i < 4; ++i)
      af[i] = *(const bf16x8_t*)&Ap[((wr << 6) + i * 16 + mrow) * 32 + kq];
#pragma unroll
    for (int j = 0; j < 4; ++j)
      bfr[j] = *(const bf16x8_t*)&Bp[((wcol << 6) + j * 16 + mrow) * 32 + kq];
    __builtin_amdgcn_s_setprio(1);
#pragma unroll
    for (int i = 0; i < 4; ++i)
#pragma unroll
      for (int j = 0; j < 4; ++j)
        acc[i][j] = __builtin_amdgcn_mfma_f32_16x16x32_bf16(af[i], bfr[j], acc[i][j], 0, 0, 0);
    __builtin_amdgcn_s_setprio(0);
  };

  // prologue: three stages in flight (3 loads each = 9 outstanding)
  stage_d3(gs, ws, m0, n0, 0,  As[0], Bs[0], rowU, chkU);
  stage_d3(gs, ws, m0, n0, 32, As[1], Bs[1], rowU, chkU);
  stage_d3(gs, ws, m0, n0, 64, As[2], Bs[2], rowU, chkU);

  for (int t = 0; t < 13; ++t) {
    asm volatile("s_waitcnt vmcnt(6)" ::: "memory");   // stage t landed (own)
    __builtin_amdgcn_sched_barrier(0);
    __builtin_amdgcn_s_barrier();                       // everyone's landed
    __builtin_amdgcn_sched_barrier(0);

    const int s = t % 3;
    compute(As[s], Bs[s]);

    __builtin_amdgcn_sched_barrier(0);
    __builtin_amdgcn_s_barrier();                       // all reads of buf done
    __builtin_amdgcn_sched_barrier(0);
    stage_d3(gs, ws, m0, n0, (t + 3) * 32, As[s], Bs[s], rowU, chkU);
  }
  // t = 13 (stages 13,14,15 outstanding = 9 loads)
  asm volatile("s_waitcnt vmcnt(6)" ::: "memory");
  __builtin_amdgcn_sched_barrier(0);
  __builtin_amdgcn_s_barrier();
  __builtin_amdgcn_sched_barrier(0);
  compute(As[1], Bs[1]);
  // t = 14
  asm volatile("s_waitcnt vmcnt(3)" ::: "memory");
  __builtin_amdgcn_sched_barrier(0);
  __builtin_amdgcn_s_barrier();
  __builtin_amdgcn_sched_barrier(0);
  compute(As[2], Bs[2]);
  // t = 15
  asm volatile("s_waitcnt vmcnt(0)" ::: "memory");
  __builtin_amdgcn_sched_barrier(0);
  __builtin_amdgcn_s_barrier();
  __builtin_amdgcn_sched_barrier(0);
  compute(As[0], Bs[0]);

  const int rbase = (lane >> 4) << 2;
#pragma unroll
  for (int i = 0; i < 4; ++i)
#pragma unroll
    for (int j = 0; j < 4; ++j)
#pragma unroll
      for (int r = 0; r < 4; ++r) {
        int row = (wr << 6) + i * 16 + rbase + r;
        int col = n0 + (wcol << 6) + j * 16 + mrow;
        float v = fmaxf(acc[i][j][r], 0.f);
        hs[(m0 + row) * F_ + col] = bf16s(v);
      }
}

// ---------------------------------------------------------------------------
// gemm_h2_ip (r6-green FALLBACK, verbatim): in-place depth-2, BN=512.
// ---------------------------------------------------------------------------
__device__ __forceinline__ void stage_ip(const short* gs, const short* ws,
                                         long long m0, int kc,
                                         short* As, short* Bs,
                                         int rowU, int chkU) {
  gload16(gs + (m0 + rowU) * F_ + kc + chkU, As + rowU * 32 + chkU);
#pragma unroll
  for (int it = 0; it < 4; ++it)
    gload16(ws + (it * 128 + rowU) * F_ + kc + chkU,
            Bs + (it * 128 + rowU) * 32 + chkU);
}

__global__ __launch_bounds__(512, 2) void gemm_h2_ip(
    __hip_bfloat16* __restrict__ gbuf, const __hip_bfloat16* __restrict__ w2bf)
{
  __shared__ __align__(16) short As[2][128 * 32];  // 16 KB
  __shared__ __align__(16) short Bs[2][512 * 32];  // 64 KB

  short* gs = (short*)gbuf;
  const short* ws = (const short*)w2bf;

  const int tid = threadIdx.x;
  const long long m0 = (long long)blockIdx.x * 128;
  const int wave8 = tid >> 6, lane = tid & 63;
  const int wr = wave8 >> 2, wcol = wave8 & 3;
  const int rowU = tid >> 2, chkU = (tid & 3) * 8;
  const int mrow = lane & 15, kq = (lane >> 4) * 8;

  f32x4_t acc[4][8];
#pragma unroll
  for (int i = 0; i < 4; ++i)
#pragma unroll
    for (int j = 0; j < 8; ++j) acc[i][j] = (f32x4_t){0.f, 0.f, 0.f, 0.f};

  auto compute = [&](const short* Ap, const short* Bp) {
    bf16x8_t af[4], bfr[8];
#pragma unroll
    for (int i = 0; i < 4; ++i)
      af[i] = *(const bf16x8_t*)&Ap[((wr << 6) + i * 16 + mrow) * 32 + kq];
#pragma unroll
    for (int j = 0; j < 8; ++j)
      bfr[j] = *(const bf16x8_t*)&Bp[((wcol << 7) + j * 16 + mrow) * 32 + kq];
    __builtin_amdgcn_s_setprio(1);
#pragma unroll
    for (int i = 0; i < 4; ++i)
#pragma unroll
      for (int j = 0; j < 8; ++j)
        acc[i][j] = __builtin_amdgcn_mfma_f32_16x16x32_bf16(af[i], bfr[j], acc[i][j], 0, 0, 0);
    __builtin_amdgcn_s_setprio(0);
  };

  stage_ip(gs, ws, m0, 0,  As[0], Bs[0], rowU, chkU);
  stage_ip(gs, ws, m0, 32, As[1], Bs[1], rowU, chkU);

  for (int t = 0; t < 14; ++t) {
    asm volatile("s_waitcnt vmcnt(5)" ::: "memory");
    __builtin_amdgcn_sched_barrier(0);
    __builtin_amdgcn_s_barrier();
    __builtin_amdgcn_sched_barrier(0);

    compute(As[t & 1], Bs[t & 1]);

    __builtin_amdgcn_sched_barrier(0);
    __builtin_amdgcn_s_barrier();
    __builtin_amdgcn_sched_barrier(0);
    stage_ip(gs, ws, m0, (t + 2) * 32, As[t & 1], Bs[t & 1], rowU, chkU);
  }
  asm volatile("s_waitcnt vmcnt(5)" ::: "memory");
  __builtin_amdgcn_sched_barrier(0);
  __builtin_amdgcn_s_barrier();
  __builtin_amdgcn_sched_barrier(0);
  compute(As[0], Bs[0]);
  asm volatile("s_waitcnt vmcnt(0)" ::: "memory");
  __builtin_amdgcn_sched_barrier(0);
  __builtin_amdgcn_s_barrier();
  __builtin_amdgcn_sched_barrier(0);
  compute(As[1], Bs[1]);

  const int rbase = (lane >> 4) << 2;
#pragma unroll
  for (int i = 0; i < 4; ++i)
#pragma unroll
    for (int j = 0; j < 8; ++j)
#pragma unroll
      for (int r = 0; r < 4; ++r) {
        int row = (wr << 6) + i * 16 + rbase + r;
        int col = (wcol << 7) + j * 16 + mrow;
        float v = fmaxf(acc[i][j][r], 0.f);
        gs[(m0 + row) * F_ + col] = bf16s(v);
      }
}

// ---------------------------------------------------------------------------
// gemm_feat v3 (this round): r9 lockstep structure (64 BK=64 phases,
// 2 barriers/phase — r10's 128-substage pipeline regressed: 2x barriers +
// drift killed L2 reuse, FETCH 98->181MB) + B-DOUBLE-BUFFER counted vmcnt:
//   A single 16 KB @0; B 2x32 KB @16384/@49152 (= 80 KB, proven 2-blk/CU).
//   Phase p: vmcnt(4) [B(p)+A(p) landed, B(p+1) in flight] ; barrier ;
//   compute(p) ; barrier ; issue A(p+1) then B(p+2).
//   Issue order B(p) < A(p) < B(p+1) => in-order retirement makes vmcnt(4)
//   retire exactly B(p)+A(p).  Drift bounded to 1 phase -> locality kept.
// ---------------------------------------------------------------------------
__global__ __launch_bounds__(512, 2) void gemm_feat(
    const __hip_bfloat16* __restrict__ h2g, const __hip_bfloat16* __restrict__ wmTg,
    float* __restrict__ out)
{
  __shared__ __align__(16) char smem[81920];
  float* sM = (float*)smem;                  // merge [32][132]  (16.9 KB)
  float* sT = (float*)smem;                  // transpose [64][65] (16.6 KB)

  const short* h2s  = (const short*)h2g;
  const short* wmTs = (const short*)wmTg;

  const int tid = threadIdx.x;
  const int bx = blockIdx.x;
  const int mt = bx & 127, nt = bx >> 7;     // XCD-aware: same mt -> same bx%8
  const long long m0 = (long long)mt * 64;
  const int n0 = nt * 128;

  const int wave8 = tid >> 6;
  const int half = wave8 >> 2;      // K-half of this wave
  const int wave = wave8 & 3;
  const int lane = tid & 63;
  const int wr = wave >> 1, wc = wave & 1;   // rows wr*32, cols wc*64
  const int mrow = lane & 15;
  const int kq = (lane >> 4) * 8;

  const short* aBase = h2s + m0 * K_TOT;
  const short* bBase = wmTs + (long long)n0 * K_TOT;

  const int rowB = tid >> 2, chkB = (tid & 3) * 8;       // B: 128 rows
  const int hA = tid >> 8;                               // A: half this thread stages
  const int rA = (tid & 255) >> 2;
  const int kA = (tid & 3) * 8;

  f32x4_t acc[2][4];
#pragma unroll
  for (int i = 0; i < 2; ++i)
#pragma unroll
    for (int j = 0; j < 4; ++j) acc[i][j] = (f32x4_t){0.f, 0.f, 0.f, 0.f};

  // A single buffer @0: (h*8192 + s*4096); B double @16384 + (p&1)*32768,
  // within: (h*2+s)*8192
  auto stageA = [&](int p) {   // 2 loads/thread
#pragma unroll
    for (int s = 0; s < 2; ++s)
      gload16(aBase + (long long)rA * K_TOT + hA * 4096 + p * 64 + s * 32 + kA,
              (short*)(smem + hA * 8192 + s * 4096) + rA * 32 + kA);
  };
  auto stageB = [&](int p) {   // 4 loads/thread
    char* bb = smem + 16384 + (p & 1) * 32768;
#pragma unroll
    for (int h = 0; h < 2; ++h)
#pragma unroll
      for (int s = 0; s < 2; ++s)
        gload16(bBase + (long long)rowB * K_TOT + h * 4096 + p * 64 + s * 32 + chkB,
                (short*)(bb + (h * 2 + s) * 8192) + rowB * 32 + chkB);
  };
  auto computeP = [&](int p) {
    char* bb = smem + 16384 + (p & 1) * 32768;
#pragma unroll
    for (int s = 0; s < 2; ++s) {
      const short* AsH = (const short*)(smem + half * 8192 + s * 4096);
      const short* BsH = (const short*)(bb + (half * 2 + s) * 8192);
      bf16x8_t af[2], bfr[4];
#pragma unroll
      for (int i = 0; i < 2; ++i)
        af[i] = *(const bf16x8_t*)&AsH[((wr << 5) + i * 16 + mrow) * 32 + kq];
#pragma unroll
      for (int j = 0; j < 4; ++j)
        bfr[j] = *(const bf16x8_t*)&BsH[((wc << 6) + j * 16 + mrow) * 32 + kq];
      __builtin_amdgcn_s_setprio(1);
#pragma unroll
      for (int i = 0; i < 2; ++i)
#pragma unroll
        for (int j = 0; j < 4; ++j)
          acc[i][j] = __builtin_amdgcn_mfma_f32_16x16x32_bf16(af[i], bfr[j], acc[i][j], 0, 0, 0);
      __builtin_amdgcn_s_setprio(0);
    }
  };

  // prologue: issue B(0), A(0), B(1) -> queue [B0(4), A0(2), B1(4)] = 10
  stageB(0);
  __builtin_amdgcn_sched_barrier(0);
  stageA(0);
  __builtin_amdgcn_sched_barrier(0);
  stageB(1);

  for (int p = 0; p < 62; ++p) {
    asm volatile("s_waitcnt vmcnt(4)" ::: "memory");  // B(p)+A(p) landed (own)
    __builtin_amdgcn_sched_barrier(0);
    __builtin_amdgcn_s_barrier();                      // everyone's landed
    __builtin_amdgcn_sched_barrier(0);

    computeP(p);

    __builtin_amdgcn_sched_barrier(0);
    __builtin_amdgcn_s_barrier();                      // all reads done
    __builtin_amdgcn_sched_barrier(0);
    stageA(p + 1);
    __builtin_amdgcn_sched_barrier(0);
    stageB(p + 2);
  }
  // p = 62: queue [B62(4), A62(2), B63(4)]
  asm volatile("s_waitcnt vmcnt(4)" ::: "memory");
  __builtin_amdgcn_sched_barrier(0);
  __builtin_amdgcn_s_barrier();
  __builtin_amdgcn_sched_barrier(0);
  computeP(62);
  __builtin_amdgcn_sched_barrier(0);
  __builtin_amdgcn_s_barrier();
  __builtin_amdgcn_sched_barrier(0);
  stageA(63);                                          // queue [B63(4), A63(2)]
  // p = 63
  asm volatile("s_waitcnt vmcnt(0)" ::: "memory");
  __builtin_amdgcn_sched_barrier(0);
  __builtin_amdgcn_s_barrier();
  __builtin_amdgcn_sched_barrier(0);
  computeP(63);

  // all loads landed; separate compute from epilogue smem reuse
  __builtin_amdgcn_sched_barrier(0);
  __builtin_amdgcn_s_barrier();
  __builtin_amdgcn_sched_barrier(0);

  // merge: half-1 accs into half-0 waves, 2 row-rounds (32 rows each) via sM
  const int rq = (lane >> 4) << 2;
#pragma unroll
  for (int r = 0; r < 2; ++r) {
    if (half == 1 && wr == r) {
#pragma unroll
      for (int i = 0; i < 2; ++i)
#pragma unroll
        for (int j = 0; j < 4; ++j)
#pragma unroll
          for (int rr = 0; rr < 4; ++rr)
            sM[(i * 16 + rq + rr) * 132 + (wc << 6) + j * 16 + mrow] = acc[i][j][rr];
    }
    __syncthreads();
    if (half == 0 && wr == r) {
#pragma unroll
      for (int i = 0; i < 2; ++i)
#pragma unroll
        for (int j = 0; j < 4; ++j)
#pragma unroll
          for (int rr = 0; rr < 4; ++rr)
            acc[i][j][rr] += sM[(i * 16 + rq + rr) * 132 + (wc << 6) + j * 16 + mrow];
    }
    __syncthreads();
  }

  // epilogue: transpose col-chunks of 64 via sT, store unnormalized out[b][f][t]
  const int b = (int)(m0 >> 11);
  const int t0 = (int)(m0 & 2047);
#pragma unroll
  for (int cch = 0; cch < 2; ++cch) {
    if (half == 0 && wc == cch) {
#pragma unroll
      for (int i = 0; i < 2; ++i)
#pragma unroll
        for (int j = 0; j < 4; ++j)
#pragma unroll
          for (int rr = 0; rr < 4; ++rr)
            sT[((wr << 5) + i * 16 + rq + rr) * 65 + j * 16 + mrow] = acc[i][j][rr];
    }
    __syncthreads();
    long long ob = (long long)b * (F_ * T_) + (long long)(n0 + cch * 64) * T_ + t0;
    for (int idx = tid; idx < 64 * 64; idx += 512) {
      int f = idx >> 6, m = idx & 63;
      out[ob + (long long)f * T_ + m] = sT[m * 65 + f];
    }
    __syncthreads();
  }
}

// ---------------------------------------------------------------------------
// LN in-place on out[b][f][t]: per (b,t) normalize over f
// ---------------------------------------------------------------------------
__global__ __launch_bounds__(256) void ln_inplace(
    float* __restrict__ out, const float* __restrict__ lnw, const float* __restrict__ lnb)
{
  __shared__ float sF[F_ * 17];
  __shared__ float red[512];
  __shared__ float smu[16], srstd[16];

  const int tid = threadIdx.x;
  const int p0 = blockIdx.x << 4;
  const int b = p0 >> 11, t0 = p0 & 2047;
  long long ob = (long long)b * (F_ * T_) + t0;

  for (int idx = tid; idx < F_ * 16; idx += 256) {
    int f = idx >> 4, m = idx & 15;
    sF[f * 17 + m] = out[ob + (long long)f * T_ + m];
  }
  __syncthreads();

  {
    int m = tid & 15, s = tid >> 4;
    float sum = 0.f, sq = 0.f;
    for (int f = s; f < F_; f += 16) {
      float v = sF[f * 17 + m];
      sum += v; sq += v * v;
    }
    red[tid] = sum;
    red[256 + tid] = sq;
  }
  __syncthreads();
  if (tid < 16) {
    float sum = 0.f, sq = 0.f;
#pragma unroll
    for (int s = 0; s < 16; ++s) { sum += red[s * 16 + tid]; sq += red[256 + s * 16 + tid]; }
    float mu = sum * (1.f / F_);
    float var = sq * (1.f / F_) - mu * mu;
    smu[tid] = mu;
    srstd[tid] = rsqrtf(var + LN_EPS);
  }
  __syncthreads();

  for (int idx = tid; idx < F_ * 16; idx += 256) {
    int f = idx >> 4, m = idx & 15;
    float v = (sF[f * 17 + m] - smu[m]) * srstd[m] * lnw[f] + lnb[f];
    out[ob + (long long)f * T_ + m] = v;
  }
}

// ---------------------------------------------------------------------------
extern "C" void kernel_launch(void* const* d_in, const int* in_sizes, int n_in,
                              void* d_out, int out_size, void* d_ws, size_t ws_size,
                              hipStream_t stream)
{
  const float* bbox      = (const float*)d_in[0];
  const int*   cls       = (const int*)d_in[1];
  const float* edge      = (const float*)d_in[2];
  const float* W_lin     = (const float*)d_in[3];
  const float* emb_table = (const float*)d_in[4];
  const float* W1        = (const float*)d_in[5];
  const float* W2        = (const float*)d_in[6];
  const float* Wm        = (const float*)d_in[7];
  const float* lnw       = (const float*)d_in[8];
  const float* lnb       = (const float*)d_in[9];
  float* out = (float*)d_out;

  float* emb1 = (float*)d_ws;
  float* wbox = emb1 + EMB1_N;
  __hip_bfloat16* w2bf = (__hip_bfloat16*)(wbox + WBOX_N);
  __hip_bfloat16* wmT  = w2bf + W2BF_N;
  __hip_bfloat16* wsBase = wmT + WMT_N;   // scratch region start

  const size_t base_bytes =
      (size_t)(EMB1_N + WBOX_N) * 4 + (size_t)(W2BF_N + WMT_N) * 2;
  const size_t tier1 = base_bytes + 2ULL * (size_t)GBUF_N * 2;          // g + h2
  const size_t tier2 = base_bytes + (size_t)GBUF_N + (size_t)GBUF_N * 2; // g/2 + h2

  precompute_small<<<(EMB1_N + WBOX_N + W2BF_N) / 256, 256, 0, stream>>>(
      emb_table, W1, W_lin, W2, emb1, wbox, w2bf);
  precompute_wmT<<<F_, 256, 0, stream>>>(Wm, wmT);

  if (ws_size >= tier1) {
    // full g + full h2, single pass
    __hip_bfloat16* gbuf  = wsBase;
    __hip_bfloat16* h2buf = gbuf + GBUF_N;
    k_h1g<<<B_ * T_, 256, 0, stream>>>(bbox, cls, edge, emb1, wbox, gbuf, 0);
    gemm_h2_d3<<<2048, 512, 0, stream>>>(gbuf, w2bf, h2buf);
    gemm_feat<<<512, 512, 0, stream>>>(h2buf, wmT, out);
  } else if (ws_size >= tier2) {
    // half-g scratch (reused), full h2; gemm_feat keeps full grid
    __hip_bfloat16* gHalf = wsBase;                       // GBUF_N/2 elems
    __hip_bfloat16* h2buf = gHalf + GBUF_N / 2;           // GBUF_N elems
    for (int c = 0; c < 2; ++c) {
      k_h1g<<<B_ * T_ / 2, 256, 0, stream>>>(
          bbox, cls, edge, emb1, wbox, gHalf, c * (B_ * T_ / 2));
      gemm_h2_d3<<<1024, 512, 0, stream>>>(
          gHalf, w2bf, h2buf + (long long)c * (GBUF_N / 2));
    }
    gemm_feat<<<512, 512, 0, stream>>>(h2buf, wmT, out);
  } else {
    // r8-green fallback: in-place depth-2
    __hip_bfloat16* gbuf = wsBase;
    k_h1g<<<B_ * T_, 256, 0, stream>>>(bbox, cls, edge, emb1, wbox, gbuf, 0);
    gemm_h2_ip<<<1024, 512, 0, stream>>>(gbuf, w2bf);
    gemm_feat<<<512, 512, 0, stream>>>(gbuf, wmT, out);
  }
  ln_inplace<<<B_ * T_ / 16, 256, 0, stream>>>(out, lnw, lnb);
}